// Round 1
// baseline (63.910 us; speedup 1.0000x reference)
//
#include <hip/hip_runtime.h>
#include <math.h>

#define B_ 4
#define C_ 2048
#define T_ 8192
#define NCHUNK 8
#define CHUNK (C_ / NCHUNK)   // 256

// Block: 512 threads = 64 t-columns (lanes) x 8 C-chunks (waves).
// Each thread: online log2-domain logsumexp over its 256-row chunk of the
// label-modified logits; LDS merge across chunks; wave0 reduces 64 L values
// and atomicAdds per-b partial sums into d_ws.
__global__ __launch_bounds__(512)
void adms_partial(const float* __restrict__ logits,
                  const int* __restrict__ target,
                  float* __restrict__ accum /* [2*B_]: sums then counts */)
{
    constexpr float K   = 30.0f * 1.4426950408889634f;         // S * log2(e)
    constexpr float MM  = 30.0f * 0.4f * 1.4426950408889634f;  // S*M * log2(e)
    constexpr float LN2 = 0.6931471805599453f;

    const int tl    = threadIdx.x & 63;   // t within tile
    const int chunk = threadIdx.x >> 6;   // 0..7
    const int tilesPerB = T_ / 64;        // 128
    const int b = blockIdx.x / tilesPerB;
    const int t = (blockIdx.x % tilesPerB) * 64 + tl;

    const int raw   = target[b * T_ + t];
    const bool valid = (raw != -1);
    const int lbl   = valid ? raw : 0;

    const float* col = logits + ((size_t)b * C_) * (size_t)T_ + (size_t)t;
    const int c0 = chunk * CHUNK;

    float m0 = -INFINITY, s0 = 0.f;
    float m1 = -INFINITY, s1 = 0.f;
    float xl = 0.f;

    #pragma unroll 4
    for (int i = 0; i < CHUNK; i += 2) {
        const int ca = c0 + i;
        const int cb = c0 + i + 1;
        float w0 = col[(size_t)ca * T_];
        float w1 = col[(size_t)cb * T_];
        float x0 = w0 * K;
        float x1 = w1 * K;
        if (ca == lbl) { x0 -= MM; xl = x0; }
        if (cb == lbl) { x1 -= MM; xl = x1; }
        float n0 = fmaxf(m0, x0);
        s0 = s0 * exp2f(m0 - n0) + exp2f(x0 - n0);
        m0 = n0;
        float n1 = fmaxf(m1, x1);
        s1 = s1 * exp2f(m1 - n1) + exp2f(x1 - n1);
        m1 = n1;
    }
    float mp = fmaxf(m0, m1);
    float sp = s0 * exp2f(m0 - mp) + s1 * exp2f(m1 - mp);

    __shared__ float lds_m[NCHUNK][64];
    __shared__ float lds_s[NCHUNK][64];
    __shared__ float lds_xl[64];

    lds_m[chunk][tl] = mp;
    lds_s[chunk][tl] = sp;
    if (lbl >= c0 && lbl < c0 + CHUNK) lds_xl[tl] = xl;  // exactly one writer per tl
    __syncthreads();

    if (chunk == 0) {
        float M = -INFINITY;
        #pragma unroll
        for (int k = 0; k < NCHUNK; ++k) M = fmaxf(M, lds_m[k][tl]);
        float S = 0.f;
        #pragma unroll
        for (int k = 0; k < NCHUNK; ++k) S += lds_s[k][tl] * exp2f(lds_m[k][tl] - M);
        float lse2 = M + log2f(S);
        float L = (lds_xl[tl] - lse2) * LN2;
        float contrib = valid ? -L : 0.f;   // accumulate -L directly
        float cnt     = valid ? 1.f : 0.f;
        #pragma unroll
        for (int off = 32; off; off >>= 1) {
            contrib += __shfl_down(contrib, off);
            cnt     += __shfl_down(cnt, off);
        }
        if (tl == 0) {
            atomicAdd(&accum[b], contrib);
            atomicAdd(&accum[B_ + b], cnt);
        }
    }
}

__global__ void adms_final(const float* __restrict__ accum, float* __restrict__ out)
{
    float acc = 0.f;
    #pragma unroll
    for (int b = 0; b < B_; ++b) acc += accum[b] / accum[B_ + b];
    out[0] = acc / (float)B_;
}

extern "C" void kernel_launch(void* const* d_in, const int* in_sizes, int n_in,
                              void* d_out, int out_size, void* d_ws, size_t ws_size,
                              hipStream_t stream) {
    const float* logits = (const float*)d_in[0];
    const int*   target = (const int*)d_in[1];
    float* out   = (float*)d_out;
    float* accum = (float*)d_ws;

    hipMemsetAsync(accum, 0, 2 * B_ * sizeof(float), stream);
    dim3 grid(B_ * (T_ / 64));
    adms_partial<<<grid, 512, 0, stream>>>(logits, target, accum);
    adms_final<<<1, 1, 0, stream>>>(accum, out);
}